// Round 11
// baseline (529.245 us; speedup 1.0000x reference)
//
#include <hip/hip_runtime.h>
#include <hip/hip_bf16.h>
#include <cstdint>
#include <cstddef>

// ---------------------------------------------------------------------------
// RGNN_53755810677120 — round 11.
//   pk2 (fp32x2 -> packed bf16x2) now uses gfx950 HW v_cvt_pk_bf16_f32
//   (guarded by __has_builtin; manual RNE fallback). attn4 was measured
//   VALU-issue-bound (59% VALUBusy) with ~200 VALU ops/tile-chain in manual
//   bf16 packing — this collapses that to ~22. All else as round 10.
// ---------------------------------------------------------------------------

typedef __attribute__((ext_vector_type(8))) short bf16x8;
typedef __attribute__((ext_vector_type(4))) float f32x4;
typedef __attribute__((ext_vector_type(2))) float f32x2;

#if defined(__has_builtin)
#if __has_builtin(__builtin_amdgcn_cvt_pk_fp8_f32) && __has_builtin(__builtin_amdgcn_cvt_pk_f32_fp8)
#define HW_FP8 1
#endif
#if __has_builtin(__builtin_amdgcn_cvt_pk_bf16_f32)
#define HW_PKBF16 1
#endif
#endif

__device__ inline short f2bf(float f) {
    union { float f; unsigned u; } v; v.f = f;
    unsigned r = (v.u + 0x7FFFu + ((v.u >> 16) & 1u)) >> 16;   // RNE
    return (short)r;
}
__device__ inline float bf2f(unsigned short b) {
    union { unsigned u; float f; } v; v.u = ((unsigned)b) << 16;
    return v.f;
}
#ifdef HW_PKBF16
typedef __attribute__((ext_vector_type(2))) __bf16 bf16x2_t;
__device__ inline unsigned pk2(float a, float b) {
    union { bf16x2_t v; unsigned u; } c;
    c.v = __builtin_amdgcn_cvt_pk_bf16_f32(a, b);
    return c.u;
}
#else
__device__ inline unsigned pk2(float a, float b) {
    return (unsigned)(unsigned short)f2bf(a) |
           ((unsigned)(unsigned short)f2bf(b) << 16);
}
#endif

#ifndef HW_FP8
__device__ inline unsigned char f2fp8_sw(float f) {
    unsigned s = (__float_as_uint(f) >> 31) & 1u;
    float a = fminf(fabsf(f), 448.f);
    unsigned char bits;
    if (a < 0.015625f) {
        bits = (unsigned char)__float2int_rn(a * 512.f);
    } else {
        int e; float m = frexpf(a, &e);
        int mf = __float2int_rn(m * 16.f);
        if (mf == 16) { mf = 8; e += 1; }
        int ef = e - 1 + 7;
        if (ef > 15) { ef = 15; mf = 14; }
        bits = (unsigned char)((ef << 3) | (mf & 7));
    }
    return (unsigned char)((s << 7) | bits);
}
__device__ inline float fp82f_sw(unsigned b) {
    int s = (b >> 7) & 1, e = (b >> 3) & 15, m = b & 7;
    float v = e ? ldexpf((float)(8 + m), e - 10) : ldexpf((float)m, -9);
    return s ? -v : v;
}
#endif

__device__ inline unsigned pk4fp8(float v0, float v1, float v2, float v3) {
#ifdef HW_FP8
    int w = __builtin_amdgcn_cvt_pk_fp8_f32(v0, v1, 0, false);
    w = __builtin_amdgcn_cvt_pk_fp8_f32(v2, v3, w, true);
    return (unsigned)w;
#else
    return (unsigned)f2fp8_sw(v0) | ((unsigned)f2fp8_sw(v1) << 8) |
           ((unsigned)f2fp8_sw(v2) << 16) | ((unsigned)f2fp8_sw(v3) << 24);
#endif
}
__device__ inline float2 up2fp8(unsigned short raw) {
#ifdef HW_FP8
    f32x2 f = __builtin_amdgcn_cvt_pk_f32_fp8((int)(unsigned)raw, false);
    return make_float2(f[0], f[1]);
#else
    return make_float2(fp82f_sw(raw & 0xffu), fp82f_sw((raw >> 8) & 0xffu));
#endif
}

// ---------------------------- weight prep + workspace zero ------------------
__global__ __launch_bounds__(64) void wprep_kernel(
    const float* __restrict__ qkv, const float* __restrict__ fw1,
    const float* __restrict__ fw2, unsigned short* __restrict__ wpack,
    int* __restrict__ bcnt, int* __restrict__ gres,
    float* __restrict__ gsum, float* __restrict__ gcnt)
{
    const int pi = blockIdx.x;
    const int lane = threadIdx.x;
    const int gid = pi * 64 + lane;
    for (int i = gid; i < 256; i += 512) { bcnt[i] = 0; gres[i] = 0; }
    for (int i = gid; i < 64 * 128; i += 512) gsum[i] = 0.f;
    if (gid < 64) gcnt[gid] = 0.f;

    const int q = lane >> 4, m = lane & 15;
    const float* Wq = qkv + (size_t)pi * 32 * 96;
    const float* W1 = fw1 + (size_t)pi * 32 * 32;
    const float* W2 = fw2 + (size_t)pi * 32 * 32;
    unsigned short* dst = wpack + (size_t)pi * 10 * 64 * 8;
#pragma unroll
    for (int ci = 0; ci < 6; ++ci)
#pragma unroll
        for (int j = 0; j < 8; ++j)
            dst[(ci * 64 + lane) * 8 + j] =
                (unsigned short)f2bf(Wq[(q * 8 + j) * 96 + ci * 16 + m]);
#pragma unroll
    for (int t = 0; t < 2; ++t)
#pragma unroll
        for (int j = 0; j < 8; ++j) {
            dst[((6 + t) * 64 + lane) * 8 + j] =
                (unsigned short)f2bf(W1[(q * 8 + j) * 32 + t * 16 + m]);
            dst[((8 + t) * 64 + lane) * 8 + j] =
                (unsigned short)f2bf(W2[(q * 8 + j) * 32 + t * 16 + m]);
        }
}

// ---------------------------- encoder --------------------------------------
__global__ __launch_bounds__(128) void enc_kernel(
    const float* __restrict__ x, const float* __restrict__ Wemb,
    unsigned short* __restrict__ h, int N)
{
    __shared__ float sxr[8 * 112];
    __shared__ float spe[128];
    __shared__ float sW[1024];
    const int t = threadIdx.x;
    const int n0 = blockIdx.x * 8;

    {
        int s = t >> 5, f = t & 31;
        int i2 = f >> 1;
        float div = __expf(-(float)(2 * i2) * (logf(10000.0f) / 32.0f));
        float ang = (float)s * div;
        spe[t] = (f & 1) ? cosf(ang) : sinf(ang);
    }
    for (int i = t; i < 1024; i += 128) sW[i] = Wemb[i];
    for (int i = t; i < 8 * 112; i += 128) {
        int n = n0 + i / 112;
        sxr[i] = (n < N) ? x[(size_t)n0 * 112 + i] : 0.f;
    }
    __syncthreads();

    const int ts = t >> 5, c = t & 31;
    const int offs_[4] = {0, 16, 48, 80};
    const int lens_[4] = {16, 32, 32, 32};
    const int off = offs_[ts], len = lens_[ts];

    float acc[8];
#pragma unroll
    for (int i = 0; i < 8; ++i) acc[i] = 0.f;
    float pw = 0.f;
    for (int f = 0; f < 32; ++f) {
        float wv = sW[f * 32 + c];
        float pv = spe[ts * 32 + f];
        pw += pv * wv;
        if (f < len) {
#pragma unroll
            for (int i = 0; i < 8; ++i) acc[i] += sxr[i * 112 + off + f] * wv;
        }
    }
#pragma unroll
    for (int i = 0; i < 8; ++i) {
        int n = n0 + i;
        if (n < N)
            h[(size_t)n * 128 + ts * 32 + c] = (unsigned short)f2bf(acc[i] + pw);
    }
}

// ---------------------------- quad-set MFMA attention -----------------------
#define ATT_WAVES 4
#define WLDS 5376

__global__ __launch_bounds__(256, 2) void attn4_kernel(
    const unsigned short* __restrict__ in,
    unsigned short* __restrict__ outR, unsigned char* __restrict__ out3,
    const unsigned short* __restrict__ wpack,
    const float* __restrict__ fb1, const float* __restrict__ fb2,
    int pibase, int N)
{
    __shared__ char smem[ATT_WAVES * 2 * WLDS];
    const int lane = threadIdx.x & 63;
    const int wave = threadIdx.x >> 6;
    const int q = lane >> 4;
    const int m = lane & 15;

    char* wb0 = smem + wave * (2 * WLDS);

#pragma unroll
    for (int u = 0; u < 2; ++u) {
        int* p32 = (int*)(wb0 + u * WLDS + 4096);
        for (int i = lane; i < 320; i += 64) p32[i] = 0;
    }

    const f32x4 zf = {0.f, 0.f, 0.f, 0.f};
    const int pi = pibase + wave;
    unsigned char* out8 = out3 + (size_t)(wave - 1) * N * 128;

    bf16x8 wqkv[6], w1f[2], w2f[2];
    float b1r[2][4], b2r[2][4];
    {
        const unsigned short* wp = wpack + ((size_t)pi * 10 * 64 + lane) * 8;
#pragma unroll
        for (int ci = 0; ci < 6; ++ci)
            wqkv[ci] = *(const bf16x8*)(wp + ci * 64 * 8);
#pragma unroll
        for (int t = 0; t < 2; ++t) {
            w1f[t] = *(const bf16x8*)(wp + (6 + t) * 64 * 8);
            w2f[t] = *(const bf16x8*)(wp + (8 + t) * 64 * 8);
#pragma unroll
            for (int r = 0; r < 4; ++r) {
                b1r[t][r] = fb1[pi * 32 + 16 * t + q * 4 + r];
                b2r[t][r] = fb2[pi * 32 + 16 * t + q * 4 + r];
            }
        }
    }

    const int nsuper = (N + 7) >> 3;
    for (int stile = blockIdx.x; stile < nsuper; stile += gridDim.x) {
        const int n0 = stile * 8;

        bf16x8 ax[2];
#pragma unroll
        for (int u = 0; u < 2; ++u) {
            bf16x8 a = {0, 0, 0, 0, 0, 0, 0, 0};
            int nm = n0 + 4 * u + (m >> 2);
            if (nm < N)
                a = *(const bf16x8*)(in + (size_t)(n0 + 4 * u) * 128 + m * 32 + q * 8);
            ax[u] = a;
        }

#pragma unroll
        for (int u = 0; u < 2; ++u) {
            char* wbu = wb0 + u * WLDS;
            short* Qb = (short*)(wbu);          // [16][40] Q (also Y)
            short* Kb = (short*)(wbu + 1280);   // [16][40] K (also Z)
            short* VT = (short*)(wbu + 2560);   // [32][24] V^T
            short* Pb = (short*)(wbu + 4096);   // [16][40] P

            f32x4 aQ[2], aK[2], aV[2];
#pragma unroll
            for (int t = 0; t < 2; ++t) {
                aQ[t] = __builtin_amdgcn_mfma_f32_16x16x32_bf16(wqkv[t],     ax[u], zf, 0, 0, 0);
                aK[t] = __builtin_amdgcn_mfma_f32_16x16x32_bf16(wqkv[2 + t], ax[u], zf, 0, 0, 0);
                aV[t] = __builtin_amdgcn_mfma_f32_16x16x32_bf16(ax[u], wqkv[4 + t], zf, 0, 0, 0);
            }
#pragma unroll
            for (int t = 0; t < 2; ++t) {
                uint2 dq, dk, dv;
                dq.x = pk2(aQ[t][0], aQ[t][1]); dq.y = pk2(aQ[t][2], aQ[t][3]);
                dk.x = pk2(aK[t][0], aK[t][1]); dk.y = pk2(aK[t][2], aK[t][3]);
                dv.x = pk2(aV[t][0], aV[t][1]); dv.y = pk2(aV[t][2], aV[t][3]);
                *(uint2*)(Qb + m * 40 + 16 * t + q * 4) = dq;
                *(uint2*)(Kb + m * 40 + 16 * t + q * 4) = dk;
                *(uint2*)(VT + (16 * t + m) * 24 + q * 4) = dv;
            }

            bf16x8 aKf = *(const bf16x8*)(Kb + m * 40 + q * 8);
            bf16x8 bQf = *(const bf16x8*)(Qb + m * 40 + q * 8);
            f32x4 st = __builtin_amdgcn_mfma_f32_16x16x32_bf16(aKf, bQf, zf, 0, 0, 0);

            float v0 = st[0] * 0.1767766952966369f;
            float v1 = st[1] * 0.1767766952966369f;
            float v2 = st[2] * 0.1767766952966369f;
            float v3 = st[3] * 0.1767766952966369f;
            float mx = fmaxf(fmaxf(v0, v1), fmaxf(v2, v3));
            float e0 = __expf(v0 - mx), e1 = __expf(v1 - mx);
            float e2 = __expf(v2 - mx), e3 = __expf(v3 - mx);
            float inv = 1.0f / (e0 + e1 + e2 + e3);
            if (q == (m >> 2)) {
                uint2 dp;
                dp.x = pk2(e0 * inv, e1 * inv);
                dp.y = pk2(e2 * inv, e3 * inv);
                *(uint2*)(Pb + m * 40 + q * 4) = dp;
            }

            f32x4 y[2];
#pragma unroll
            for (int t = 0; t < 2; ++t) {
                bf16x8 aVf = {0, 0, 0, 0, 0, 0, 0, 0};
                bf16x8 bPf = {0, 0, 0, 0, 0, 0, 0, 0};
                if (q < 2) {
                    aVf = *(const bf16x8*)(VT + (16 * t + m) * 24 + q * 8);
                    bPf = *(const bf16x8*)(Pb + m * 40 + q * 8);
                }
                y[t] = __builtin_amdgcn_mfma_f32_16x16x32_bf16(aVf, bPf, zf, 0, 0, 0);
            }
#pragma unroll
            for (int t = 0; t < 2; ++t) {
                uint2 dy;
                dy.x = pk2(y[t][0], y[t][1]); dy.y = pk2(y[t][2], y[t][3]);
                *(uint2*)(Qb + m * 40 + 16 * t + q * 4) = dy;
            }

            bf16x8 bY = *(const bf16x8*)(Qb + m * 40 + q * 8);
            f32x4 z1[2];
#pragma unroll
            for (int t = 0; t < 2; ++t)
                z1[t] = __builtin_amdgcn_mfma_f32_16x16x32_bf16(w1f[t], bY, zf, 0, 0, 0);
#pragma unroll
            for (int t = 0; t < 2; ++t) {
                uint2 dz;
                dz.x = pk2(fmaxf(z1[t][0] + b1r[t][0], 0.f),
                           fmaxf(z1[t][1] + b1r[t][1], 0.f));
                dz.y = pk2(fmaxf(z1[t][2] + b1r[t][2], 0.f),
                           fmaxf(z1[t][3] + b1r[t][3], 0.f));
                *(uint2*)(Kb + m * 40 + 16 * t + q * 4) = dz;
            }

            bf16x8 bZ = *(const bf16x8*)(Kb + m * 40 + q * 8);
            f32x4 o[2];
#pragma unroll
            for (int t = 0; t < 2; ++t)
                o[t] = __builtin_amdgcn_mfma_f32_16x16x32_bf16(w2f[t], bZ, zf, 0, 0, 0);

            if (n0 + 4 * u + (m >> 2) < N) {
                if (wave == 0) {        // bf16 root
#pragma unroll
                    for (int t = 0; t < 2; ++t) {
                        uint2 dd;
                        dd.x = pk2(y[t][0] + o[t][0] + b2r[t][0],
                                   y[t][1] + o[t][1] + b2r[t][1]);
                        dd.y = pk2(y[t][2] + o[t][2] + b2r[t][2],
                                   y[t][3] + o[t][3] + b2r[t][3]);
                        *(uint2*)(outR + (size_t)(n0 + 4 * u) * 128 + m * 32 + 16 * t + q * 4) = dd;
                    }
                } else {                // fp8 e4m3, x16 scale
#pragma unroll
                    for (int t = 0; t < 2; ++t) {
                        unsigned pw8 = pk4fp8(
                            (y[t][0] + o[t][0] + b2r[t][0]) * 16.f,
                            (y[t][1] + o[t][1] + b2r[t][1]) * 16.f,
                            (y[t][2] + o[t][2] + b2r[t][2]) * 16.f,
                            (y[t][3] + o[t][3] + b2r[t][3]) * 16.f);
                        *(unsigned*)(out8 + (size_t)(n0 + 4 * u) * 128 + m * 32 + 16 * t + q * 4) = pw8;
                    }
                }
            }
        }
    }
}

// ---------------------------- fused CSR build -------------------------------
#define PA_CHUNK 4096
#define PA_SHIFT 9
#define PA_MAXB  256
#define HB_K     16

__global__ __launch_bounds__(256) void histB_kernel(
    const int* __restrict__ e0, const int* __restrict__ e1,
    const int* __restrict__ e2, int* __restrict__ bcnt, int E)
{
    __shared__ int lh[PA_MAXB];
    const int lab = blockIdx.y;
    const int* e = (lab == 0) ? e0 : (lab == 1) ? e1 : e2;
    const int t = threadIdx.x;
    for (int i = t; i < PA_MAXB; i += 256) lh[i] = 0;
    __syncthreads();
    const int base = blockIdx.x * 256 * HB_K;
#pragma unroll
    for (int k = 0; k < HB_K; ++k) {
        int i = base + k * 256 + t;
        if (i < E) atomicAdd(&lh[e[E + i] >> PA_SHIFT], 1);
    }
    __syncthreads();
    for (int i = t; i < PA_MAXB; i += 256)
        if (lh[i]) atomicAdd(&bcnt[i], lh[i]);
}

__global__ __launch_bounds__(256) void bscan_kernel(
    const int* __restrict__ bcnt, int* __restrict__ bbase)
{
    __shared__ int sd[PA_MAXB];
    const int t = threadIdx.x;
    sd[t] = bcnt[t];
    __syncthreads();
    int own = sd[t];
    for (int o = 1; o < 256; o <<= 1) {
        int v = (t >= o) ? sd[t - o] : 0;
        __syncthreads();
        sd[t] += v;
        __syncthreads();
    }
    bbase[t] = sd[t] - own;
}

__global__ __launch_bounds__(256) void placeA_kernel(
    const int* __restrict__ e0, const int* __restrict__ e1, const int* __restrict__ e2,
    const int* __restrict__ bbase, int* __restrict__ gres,
    int2* __restrict__ pairs, int E, int N)
{
    __shared__ int2 sStage[PA_CHUNK];
    __shared__ int sCnt[PA_MAXB], sScan[PA_MAXB], sCur[PA_MAXB], sGB[PA_MAXB];

    const int lab = blockIdx.y;
    const int t = threadIdx.x;
    const int base = blockIdx.x * PA_CHUNK;
    const int* e = (lab == 0) ? e0 : (lab == 1) ? e1 : e2;
    const int srcoff = lab * N;
    const int nbins = (N + (1 << PA_SHIFT) - 1) >> PA_SHIFT;

    for (int i = t; i < PA_MAXB; i += 256) { sCnt[i] = 0; sCur[i] = 0; }
    __syncthreads();

    int msrc[16], mdst[16];
    const int cnt_total = min(PA_CHUNK, E - base);
#pragma unroll
    for (int k = 0; k < 16; ++k) {
        int i = base + k * 256 + t;
        if (i < E) {
            msrc[k] = srcoff + e[i];
            int d = e[E + i];
            mdst[k] = d;
            atomicAdd(&sCnt[d >> PA_SHIFT], 1);
        } else mdst[k] = -1;
    }
    __syncthreads();

    sScan[t] = sCnt[t];
    __syncthreads();
    for (int o = 1; o < 256; o <<= 1) {
        int v = (t >= o) ? sScan[t - o] : 0;
        __syncthreads();
        sScan[t] += v;
        __syncthreads();
    }
    if (t < nbins && sCnt[t] > 0)
        sGB[t] = bbase[t] + atomicAdd(&gres[t], sCnt[t]);
    __syncthreads();

#pragma unroll
    for (int k = 0; k < 16; ++k) {
        if (mdst[k] >= 0) {
            int bin = mdst[k] >> PA_SHIFT;
            int r = atomicAdd(&sCur[bin], 1);
            sStage[(sScan[bin] - sCnt[bin]) + r] = make_int2(msrc[k], mdst[k]);
        }
    }
    __syncthreads();

    for (int i = t; i < cnt_total; i += 256) {
        int2 pr = sStage[i];
        int bin = pr.y >> PA_SHIFT;
        pairs[sGB[bin] + (i - (sScan[bin] - sCnt[bin]))] = pr;
    }
}

__global__ __launch_bounds__(512) void placeB_kernel(
    const int2* __restrict__ pairs, const int* __restrict__ bbase,
    const int* __restrict__ bcnt, int* __restrict__ offs,
    int* __restrict__ csr, int N, int nbins)
{
    __shared__ int sCnt[512], sScan[512], sFill[512];
    const int bin = blockIdx.x;
    const int t = threadIdx.x;
    const int n0 = bin << PA_SHIFT;
    const int n1 = min(n0 + 512, N);
    const int len = n1 - n0;
    const int rb  = bbase[bin];
    const int cnt = bcnt[bin];
    const int2* gp = pairs + rb;

    sCnt[t] = 0; sFill[t] = 0;
    __syncthreads();
    for (int i = t; i < cnt; i += 512)
        atomicAdd(&sCnt[gp[i].y - n0], 1);
    __syncthreads();
    sScan[t] = sCnt[t];
    __syncthreads();
    for (int o = 1; o < 512; o <<= 1) {
        int v = (t >= o) ? sScan[t - o] : 0;
        __syncthreads();
        sScan[t] += v;
        __syncthreads();
    }
    const int excl = sScan[t] - sCnt[t];
    if (t < len) offs[n0 + t] = rb + excl;
    if (bin == nbins - 1 && t == 0) offs[N] = rb + cnt;
    sScan[t] = excl;
    __syncthreads();

    for (int i = t; i < cnt; i += 512) {
        int2 pr = gp[i];
        int ln = pr.y - n0;
        int p = atomicAdd(&sFill[ln], 1);
        csr[rb + sScan[ln] + p] = pr.x;
    }
}

// ---------------------------- fused aggregation -----------------------------
__global__ __launch_bounds__(256) void agg3_kernel(
    const unsigned short* __restrict__ xtR,
    const unsigned char* __restrict__ xt3,
    const int* __restrict__ csr, const int* __restrict__ offs,
    unsigned short* __restrict__ hout, int N)
{
    int w = threadIdx.x >> 6, lane = threadIdx.x & 63;
    int dst = blockIdx.x * 4 + w;
    if (dst >= N) return;

    const ushort2* r2 = (const ushort2*)xtR;
    ushort2 rv = r2[(size_t)dst * 64 + lane];
    float2 a[8];
#pragma unroll
    for (int i = 0; i < 8; ++i) a[i] = make_float2(0.f, 0.f);

    const unsigned short* x8 = (const unsigned short*)xt3;
    const int beg = offs[dst], end = offs[dst + 1];
    int k = beg;
    for (; k + 8 <= end; k += 8) {
        int4 sa = *(const int4*)(csr + k);
        int4 sb = *(const int4*)(csr + k + 4);
        int s[8] = {sa.x, sa.y, sa.z, sa.w, sb.x, sb.y, sb.z, sb.w};
        unsigned short v[8];
#pragma unroll
        for (int i = 0; i < 8; ++i) v[i] = x8[(size_t)s[i] * 64 + lane];
#pragma unroll
        for (int i = 0; i < 8; ++i) {
            float2 f = up2fp8(v[i]);
            a[i].x += f.x; a[i].y += f.y;
        }
    }
    for (; k + 2 <= end; k += 2) {
        unsigned short v0 = x8[(size_t)csr[k] * 64 + lane];
        unsigned short v1 = x8[(size_t)csr[k + 1] * 64 + lane];
        float2 f0 = up2fp8(v0), f1 = up2fp8(v1);
        a[0].x += f0.x; a[0].y += f0.y;
        a[1].x += f1.x; a[1].y += f1.y;
    }
    for (; k < end; ++k) {
        float2 f0 = up2fp8(x8[(size_t)csr[k] * 64 + lane]);
        a[0].x += f0.x; a[0].y += f0.y;
    }
    float sx = ((a[0].x + a[1].x) + (a[2].x + a[3].x)) +
               ((a[4].x + a[5].x) + (a[6].x + a[7].x));
    float sy = ((a[0].y + a[1].y) + (a[2].y + a[3].y)) +
               ((a[4].y + a[5].y) + (a[6].y + a[7].y));
    float fx = bf2f(rv.x) + 0.0625f * sx;
    float fy = bf2f(rv.y) + 0.0625f * sy;
    ((unsigned*)hout)[(size_t)dst * 64 + lane] = pk2(fmaxf(fx, 0.f), fmaxf(fy, 0.f));
}

// ---------------------------- pool (+counts) / decoder ----------------------
__global__ __launch_bounds__(256) void pool_kernel(
    const unsigned short* __restrict__ in, const int* __restrict__ batch,
    float* __restrict__ gsum, float* __restrict__ gcnt, int N)
{
    int t = threadIdx.x;
    int j = t & 127, half = t >> 7;
    int n0 = blockIdx.x * 64 + half * 32;
    float acc = 0.f, c = 0.f; int cur = -1;
    for (int i = 0; i < 32; ++i) {
        int n = n0 + i;
        if (n >= N) break;
        int g = batch[n];
        if (g != cur) {
            if (cur >= 0) {
                atomicAdd(&gsum[cur * 128 + j], acc);
                if (j == 0) atomicAdd(&gcnt[cur], c);
            }
            cur = g; acc = 0.f; c = 0.f;
        }
        acc += bf2f(in[(size_t)n * 128 + j]);
        c += 1.f;
    }
    if (cur >= 0) {
        atomicAdd(&gsum[cur * 128 + j], acc);
        if (j == 0) atomicAdd(&gcnt[cur], c);
    }
}

__global__ __launch_bounds__(128) void dec_kernel(
    const float* __restrict__ gsum, const float* __restrict__ gcnt,
    const float* __restrict__ W1, const float* __restrict__ B1,
    const float* __restrict__ W2, const float* __restrict__ B2,
    float* __restrict__ out)
{
    __shared__ float sg[128];
    __shared__ float sh[128];
    int t = threadIdx.x, b = blockIdx.x;
    float cinv = 1.0f / fmaxf(gcnt[b], 1.0f);
    sg[t] = gsum[b * 128 + t] * cinv;
    __syncthreads();
    float acc = B1[t];
    for (int f = 0; f < 128; ++f) acc += sg[f] * W1[f * 128 + t];
    sh[t] = fmaxf(acc, 0.f) * W2[t];
    __syncthreads();
    for (int o = 64; o > 0; o >>= 1) {
        if (t < o) sh[t] += sh[t + o];
        __syncthreads();
    }
    if (t == 0) out[b] = sh[0] + B2[0];
}

// ---------------------------- launch ---------------------------------------
extern "C" void kernel_launch(void* const* d_in, const int* in_sizes, int n_in,
                              void* d_out, int out_size, void* d_ws, size_t ws_size,
                              hipStream_t stream)
{
    const float* x    = (const float*)d_in[0];
    const int*   e0   = (const int*)d_in[1];
    const int*   e1   = (const int*)d_in[2];
    const int*   e2   = (const int*)d_in[3];
    const int*   bat  = (const int*)d_in[4];
    const float* Wemb = (const float*)d_in[5];
    const float* qkv  = (const float*)d_in[6];
    const float* fw1  = (const float*)d_in[7];
    const float* fb1  = (const float*)d_in[8];
    const float* fw2  = (const float*)d_in[9];
    const float* fb2  = (const float*)d_in[10];
    const float* mw1  = (const float*)d_in[11];
    const float* mb1  = (const float*)d_in[12];
    const float* mw2  = (const float*)d_in[13];
    const float* mb2  = (const float*)d_in[14];
    const int N = in_sizes[0] / 112;
    const int E = in_sizes[1] / 2;
    float* outp = (float*)d_out;
    (void)n_in; (void)out_size; (void)ws_size;

    char* w = (char*)d_ws;
    auto alloc = [&](size_t bytes) {
        char* p = w; w += (bytes + 255) & ~(size_t)255; return p;
    };
    unsigned short* h0    = (unsigned short*)alloc((size_t)N * 128 * 2);
    unsigned short* h1    = (unsigned short*)alloc((size_t)N * 128 * 2);
    unsigned short* xtR   = (unsigned short*)alloc((size_t)N * 128 * 2);
    unsigned char*  xt3   = (unsigned char*)alloc((size_t)3 * N * 128);
    unsigned short* wpack = (unsigned short*)alloc(8 * 10 * 64 * 8 * 2);
    int*   csr   = (int*)alloc((size_t)3 * E * 4);
    int*   offs  = (int*)alloc((size_t)(N + 1) * 4);
    int*   bcnt  = (int*)alloc(PA_MAXB * 4);
    int*   bbase = (int*)alloc(PA_MAXB * 4);
    int*   gres  = (int*)alloc(PA_MAXB * 4);
    float* gsum  = (float*)alloc(64 * 128 * 4);
    float* gcnt  = (float*)alloc(64 * 4);
    int2* pairs = (int2*)xtR;   // aliased; consumed before attn4 writes xtR

    const int nbins = (N + (1 << PA_SHIFT) - 1) >> PA_SHIFT;

    wprep_kernel<<<8, 64, 0, stream>>>(qkv, fw1, fw2, wpack, bcnt, gres, gsum, gcnt);
    enc_kernel<<<(N + 7) / 8, 128, 0, stream>>>(x, Wemb, h0, N);

    histB_kernel<<<dim3((E + 256 * HB_K - 1) / (256 * HB_K), 3), 256, 0, stream>>>(
        e0, e1, e2, bcnt, E);
    bscan_kernel<<<1, 256, 0, stream>>>(bcnt, bbase);
    placeA_kernel<<<dim3((E + PA_CHUNK - 1) / PA_CHUNK, 3), 256, 0, stream>>>(
        e0, e1, e2, bbase, gres, pairs, E, N);
    placeB_kernel<<<nbins, 512, 0, stream>>>(pairs, bbase, bcnt, offs, csr, N, nbins);

    const int ATT_GRID = 1024;
    auto run_layer = [&](const unsigned short* lin, unsigned short* lout, int l) {
        attn4_kernel<<<ATT_GRID, 256, 0, stream>>>(
            lin, xtR, xt3, wpack, fb1, fb2, l * 4, N);
        agg3_kernel<<<(N + 3) / 4, 256, 0, stream>>>(xtR, xt3, csr, offs, lout, N);
    };
    run_layer(h0, h1, 0);
    run_layer(h1, h0, 1);

    pool_kernel<<<(N + 63) / 64, 256, 0, stream>>>(h0, bat, gsum, gcnt, N);
    dec_kernel<<<64, 128, 0, stream>>>(gsum, gcnt, mw1, mb1, mw2, mb2, outp);
}

// Round 12
// 496.176 us; speedup vs baseline: 1.0666x; 1.0666x over previous
//
#include <hip/hip_runtime.h>
#include <hip/hip_bf16.h>
#include <cstdint>
#include <cstddef>

// ---------------------------------------------------------------------------
// RGNN_53755810677120 — round 12.
//   pk2 (fp32x2 -> packed bf16x2) = 3 VALU ops: round-half-up adds + one
//   v_perm_b32 byte-permute (builtin_amdgcn_perm — always available).
//   attn4: launch_bounds(256,3) + grid 768 occupancy probe (no prefetch).
//   All else as round 11.
// ---------------------------------------------------------------------------

typedef __attribute__((ext_vector_type(8))) short bf16x8;
typedef __attribute__((ext_vector_type(4))) float f32x4;
typedef __attribute__((ext_vector_type(2))) float f32x2;

#if defined(__has_builtin)
#if __has_builtin(__builtin_amdgcn_cvt_pk_fp8_f32) && __has_builtin(__builtin_amdgcn_cvt_pk_f32_fp8)
#define HW_FP8 1
#endif
#if __has_builtin(__builtin_amdgcn_cvt_pk_bf16_f32)
#define HW_PKBF16 1
#endif
#endif

__device__ inline short f2bf(float f) {
    union { float f; unsigned u; } v; v.f = f;
    unsigned r = (v.u + 0x7FFFu + ((v.u >> 16) & 1u)) >> 16;   // RNE
    return (short)r;
}
__device__ inline float bf2f(unsigned short b) {
    union { unsigned u; float f; } v; v.u = ((unsigned)b) << 16;
    return v.f;
}
#ifdef HW_PKBF16
typedef __attribute__((ext_vector_type(2))) __bf16 bf16x2_t;
__device__ inline unsigned pk2(float a, float b) {
    union { bf16x2_t v; unsigned u; } c;
    c.v = __builtin_amdgcn_cvt_pk_bf16_f32(a, b);
    return c.u;
}
#else
// round-half-up (+0x8000) then pack high halves with one v_perm_b32.
// Differs from RNE only on exact-tie mantissas (p ~ 2^-16, +-1 ulp).
__device__ inline unsigned pk2(float a, float b) {
    unsigned ua = __float_as_uint(a) + 0x8000u;
    unsigned ub = __float_as_uint(b) + 0x8000u;
    return __builtin_amdgcn_perm(ub, ua, 0x07060302u);  // [b_hi16 | a_hi16]
}
#endif

#ifndef HW_FP8
__device__ inline unsigned char f2fp8_sw(float f) {
    unsigned s = (__float_as_uint(f) >> 31) & 1u;
    float a = fminf(fabsf(f), 448.f);
    unsigned char bits;
    if (a < 0.015625f) {
        bits = (unsigned char)__float2int_rn(a * 512.f);
    } else {
        int e; float m = frexpf(a, &e);
        int mf = __float2int_rn(m * 16.f);
        if (mf == 16) { mf = 8; e += 1; }
        int ef = e - 1 + 7;
        if (ef > 15) { ef = 15; mf = 14; }
        bits = (unsigned char)((ef << 3) | (mf & 7));
    }
    return (unsigned char)((s << 7) | bits);
}
__device__ inline float fp82f_sw(unsigned b) {
    int s = (b >> 7) & 1, e = (b >> 3) & 15, m = b & 7;
    float v = e ? ldexpf((float)(8 + m), e - 10) : ldexpf((float)m, -9);
    return s ? -v : v;
}
#endif

__device__ inline unsigned pk4fp8(float v0, float v1, float v2, float v3) {
#ifdef HW_FP8
    int w = __builtin_amdgcn_cvt_pk_fp8_f32(v0, v1, 0, false);
    w = __builtin_amdgcn_cvt_pk_fp8_f32(v2, v3, w, true);
    return (unsigned)w;
#else
    return (unsigned)f2fp8_sw(v0) | ((unsigned)f2fp8_sw(v1) << 8) |
           ((unsigned)f2fp8_sw(v2) << 16) | ((unsigned)f2fp8_sw(v3) << 24);
#endif
}
__device__ inline float2 up2fp8(unsigned short raw) {
#ifdef HW_FP8
    f32x2 f = __builtin_amdgcn_cvt_pk_f32_fp8((int)(unsigned)raw, false);
    return make_float2(f[0], f[1]);
#else
    return make_float2(fp82f_sw(raw & 0xffu), fp82f_sw((raw >> 8) & 0xffu));
#endif
}

// ---------------------------- weight prep + workspace zero ------------------
__global__ __launch_bounds__(64) void wprep_kernel(
    const float* __restrict__ qkv, const float* __restrict__ fw1,
    const float* __restrict__ fw2, unsigned short* __restrict__ wpack,
    int* __restrict__ bcnt, int* __restrict__ gres,
    float* __restrict__ gsum, float* __restrict__ gcnt)
{
    const int pi = blockIdx.x;
    const int lane = threadIdx.x;
    const int gid = pi * 64 + lane;
    for (int i = gid; i < 256; i += 512) { bcnt[i] = 0; gres[i] = 0; }
    for (int i = gid; i < 64 * 128; i += 512) gsum[i] = 0.f;
    if (gid < 64) gcnt[gid] = 0.f;

    const int q = lane >> 4, m = lane & 15;
    const float* Wq = qkv + (size_t)pi * 32 * 96;
    const float* W1 = fw1 + (size_t)pi * 32 * 32;
    const float* W2 = fw2 + (size_t)pi * 32 * 32;
    unsigned short* dst = wpack + (size_t)pi * 10 * 64 * 8;
#pragma unroll
    for (int ci = 0; ci < 6; ++ci)
#pragma unroll
        for (int j = 0; j < 8; ++j)
            dst[(ci * 64 + lane) * 8 + j] =
                (unsigned short)f2bf(Wq[(q * 8 + j) * 96 + ci * 16 + m]);
#pragma unroll
    for (int t = 0; t < 2; ++t)
#pragma unroll
        for (int j = 0; j < 8; ++j) {
            dst[((6 + t) * 64 + lane) * 8 + j] =
                (unsigned short)f2bf(W1[(q * 8 + j) * 32 + t * 16 + m]);
            dst[((8 + t) * 64 + lane) * 8 + j] =
                (unsigned short)f2bf(W2[(q * 8 + j) * 32 + t * 16 + m]);
        }
}

// ---------------------------- encoder --------------------------------------
__global__ __launch_bounds__(128) void enc_kernel(
    const float* __restrict__ x, const float* __restrict__ Wemb,
    unsigned short* __restrict__ h, int N)
{
    __shared__ float sxr[8 * 112];
    __shared__ float spe[128];
    __shared__ float sW[1024];
    const int t = threadIdx.x;
    const int n0 = blockIdx.x * 8;

    {
        int s = t >> 5, f = t & 31;
        int i2 = f >> 1;
        float div = __expf(-(float)(2 * i2) * (logf(10000.0f) / 32.0f));
        float ang = (float)s * div;
        spe[t] = (f & 1) ? cosf(ang) : sinf(ang);
    }
    for (int i = t; i < 1024; i += 128) sW[i] = Wemb[i];
    for (int i = t; i < 8 * 112; i += 128) {
        int n = n0 + i / 112;
        sxr[i] = (n < N) ? x[(size_t)n0 * 112 + i] : 0.f;
    }
    __syncthreads();

    const int ts = t >> 5, c = t & 31;
    const int offs_[4] = {0, 16, 48, 80};
    const int lens_[4] = {16, 32, 32, 32};
    const int off = offs_[ts], len = lens_[ts];

    float acc[8];
#pragma unroll
    for (int i = 0; i < 8; ++i) acc[i] = 0.f;
    float pw = 0.f;
    for (int f = 0; f < 32; ++f) {
        float wv = sW[f * 32 + c];
        float pv = spe[ts * 32 + f];
        pw += pv * wv;
        if (f < len) {
#pragma unroll
            for (int i = 0; i < 8; ++i) acc[i] += sxr[i * 112 + off + f] * wv;
        }
    }
#pragma unroll
    for (int i = 0; i < 8; ++i) {
        int n = n0 + i;
        if (n < N)
            h[(size_t)n * 128 + ts * 32 + c] = (unsigned short)f2bf(acc[i] + pw);
    }
}

// ---------------------------- quad-set MFMA attention -----------------------
#define ATT_WAVES 4
#define WLDS 5376

__global__ __launch_bounds__(256, 3) void attn4_kernel(
    const unsigned short* __restrict__ in,
    unsigned short* __restrict__ outR, unsigned char* __restrict__ out3,
    const unsigned short* __restrict__ wpack,
    const float* __restrict__ fb1, const float* __restrict__ fb2,
    int pibase, int N)
{
    __shared__ char smem[ATT_WAVES * 2 * WLDS];
    const int lane = threadIdx.x & 63;
    const int wave = threadIdx.x >> 6;
    const int q = lane >> 4;
    const int m = lane & 15;

    char* wb0 = smem + wave * (2 * WLDS);

#pragma unroll
    for (int u = 0; u < 2; ++u) {
        int* p32 = (int*)(wb0 + u * WLDS + 4096);
        for (int i = lane; i < 320; i += 64) p32[i] = 0;
    }

    const f32x4 zf = {0.f, 0.f, 0.f, 0.f};
    const int pi = pibase + wave;
    unsigned char* out8 = out3 + (size_t)(wave - 1) * N * 128;

    bf16x8 wqkv[6], w1f[2], w2f[2];
    float b1r[2][4], b2r[2][4];
    {
        const unsigned short* wp = wpack + ((size_t)pi * 10 * 64 + lane) * 8;
#pragma unroll
        for (int ci = 0; ci < 6; ++ci)
            wqkv[ci] = *(const bf16x8*)(wp + ci * 64 * 8);
#pragma unroll
        for (int t = 0; t < 2; ++t) {
            w1f[t] = *(const bf16x8*)(wp + (6 + t) * 64 * 8);
            w2f[t] = *(const bf16x8*)(wp + (8 + t) * 64 * 8);
#pragma unroll
            for (int r = 0; r < 4; ++r) {
                b1r[t][r] = fb1[pi * 32 + 16 * t + q * 4 + r];
                b2r[t][r] = fb2[pi * 32 + 16 * t + q * 4 + r];
            }
        }
    }

    const int nsuper = (N + 7) >> 3;
    for (int stile = blockIdx.x; stile < nsuper; stile += gridDim.x) {
        const int n0 = stile * 8;

        bf16x8 ax[2];
#pragma unroll
        for (int u = 0; u < 2; ++u) {
            bf16x8 a = {0, 0, 0, 0, 0, 0, 0, 0};
            int nm = n0 + 4 * u + (m >> 2);
            if (nm < N)
                a = *(const bf16x8*)(in + (size_t)(n0 + 4 * u) * 128 + m * 32 + q * 8);
            ax[u] = a;
        }

#pragma unroll
        for (int u = 0; u < 2; ++u) {
            char* wbu = wb0 + u * WLDS;
            short* Qb = (short*)(wbu);          // [16][40] Q (also Y)
            short* Kb = (short*)(wbu + 1280);   // [16][40] K (also Z)
            short* VT = (short*)(wbu + 2560);   // [32][24] V^T
            short* Pb = (short*)(wbu + 4096);   // [16][40] P

            f32x4 aQ[2], aK[2], aV[2];
#pragma unroll
            for (int t = 0; t < 2; ++t) {
                aQ[t] = __builtin_amdgcn_mfma_f32_16x16x32_bf16(wqkv[t],     ax[u], zf, 0, 0, 0);
                aK[t] = __builtin_amdgcn_mfma_f32_16x16x32_bf16(wqkv[2 + t], ax[u], zf, 0, 0, 0);
                aV[t] = __builtin_amdgcn_mfma_f32_16x16x32_bf16(ax[u], wqkv[4 + t], zf, 0, 0, 0);
            }
#pragma unroll
            for (int t = 0; t < 2; ++t) {
                uint2 dq, dk, dv;
                dq.x = pk2(aQ[t][0], aQ[t][1]); dq.y = pk2(aQ[t][2], aQ[t][3]);
                dk.x = pk2(aK[t][0], aK[t][1]); dk.y = pk2(aK[t][2], aK[t][3]);
                dv.x = pk2(aV[t][0], aV[t][1]); dv.y = pk2(aV[t][2], aV[t][3]);
                *(uint2*)(Qb + m * 40 + 16 * t + q * 4) = dq;
                *(uint2*)(Kb + m * 40 + 16 * t + q * 4) = dk;
                *(uint2*)(VT + (16 * t + m) * 24 + q * 4) = dv;
            }

            bf16x8 aKf = *(const bf16x8*)(Kb + m * 40 + q * 8);
            bf16x8 bQf = *(const bf16x8*)(Qb + m * 40 + q * 8);
            f32x4 st = __builtin_amdgcn_mfma_f32_16x16x32_bf16(aKf, bQf, zf, 0, 0, 0);

            float v0 = st[0] * 0.1767766952966369f;
            float v1 = st[1] * 0.1767766952966369f;
            float v2 = st[2] * 0.1767766952966369f;
            float v3 = st[3] * 0.1767766952966369f;
            float mx = fmaxf(fmaxf(v0, v1), fmaxf(v2, v3));
            float e0 = __expf(v0 - mx), e1 = __expf(v1 - mx);
            float e2 = __expf(v2 - mx), e3 = __expf(v3 - mx);
            float inv = 1.0f / (e0 + e1 + e2 + e3);
            if (q == (m >> 2)) {
                uint2 dp;
                dp.x = pk2(e0 * inv, e1 * inv);
                dp.y = pk2(e2 * inv, e3 * inv);
                *(uint2*)(Pb + m * 40 + q * 4) = dp;
            }

            f32x4 y[2];
#pragma unroll
            for (int t = 0; t < 2; ++t) {
                bf16x8 aVf = {0, 0, 0, 0, 0, 0, 0, 0};
                bf16x8 bPf = {0, 0, 0, 0, 0, 0, 0, 0};
                if (q < 2) {
                    aVf = *(const bf16x8*)(VT + (16 * t + m) * 24 + q * 8);
                    bPf = *(const bf16x8*)(Pb + m * 40 + q * 8);
                }
                y[t] = __builtin_amdgcn_mfma_f32_16x16x32_bf16(aVf, bPf, zf, 0, 0, 0);
            }
#pragma unroll
            for (int t = 0; t < 2; ++t) {
                uint2 dy;
                dy.x = pk2(y[t][0], y[t][1]); dy.y = pk2(y[t][2], y[t][3]);
                *(uint2*)(Qb + m * 40 + 16 * t + q * 4) = dy;
            }

            bf16x8 bY = *(const bf16x8*)(Qb + m * 40 + q * 8);
            f32x4 z1[2];
#pragma unroll
            for (int t = 0; t < 2; ++t)
                z1[t] = __builtin_amdgcn_mfma_f32_16x16x32_bf16(w1f[t], bY, zf, 0, 0, 0);
#pragma unroll
            for (int t = 0; t < 2; ++t) {
                uint2 dz;
                dz.x = pk2(fmaxf(z1[t][0] + b1r[t][0], 0.f),
                           fmaxf(z1[t][1] + b1r[t][1], 0.f));
                dz.y = pk2(fmaxf(z1[t][2] + b1r[t][2], 0.f),
                           fmaxf(z1[t][3] + b1r[t][3], 0.f));
                *(uint2*)(Kb + m * 40 + 16 * t + q * 4) = dz;
            }

            bf16x8 bZ = *(const bf16x8*)(Kb + m * 40 + q * 8);
            f32x4 o[2];
#pragma unroll
            for (int t = 0; t < 2; ++t)
                o[t] = __builtin_amdgcn_mfma_f32_16x16x32_bf16(w2f[t], bZ, zf, 0, 0, 0);

            if (n0 + 4 * u + (m >> 2) < N) {
                if (wave == 0) {        // bf16 root
#pragma unroll
                    for (int t = 0; t < 2; ++t) {
                        uint2 dd;
                        dd.x = pk2(y[t][0] + o[t][0] + b2r[t][0],
                                   y[t][1] + o[t][1] + b2r[t][1]);
                        dd.y = pk2(y[t][2] + o[t][2] + b2r[t][2],
                                   y[t][3] + o[t][3] + b2r[t][3]);
                        *(uint2*)(outR + (size_t)(n0 + 4 * u) * 128 + m * 32 + 16 * t + q * 4) = dd;
                    }
                } else {                // fp8 e4m3, x16 scale
#pragma unroll
                    for (int t = 0; t < 2; ++t) {
                        unsigned pw8 = pk4fp8(
                            (y[t][0] + o[t][0] + b2r[t][0]) * 16.f,
                            (y[t][1] + o[t][1] + b2r[t][1]) * 16.f,
                            (y[t][2] + o[t][2] + b2r[t][2]) * 16.f,
                            (y[t][3] + o[t][3] + b2r[t][3]) * 16.f);
                        *(unsigned*)(out8 + (size_t)(n0 + 4 * u) * 128 + m * 32 + 16 * t + q * 4) = pw8;
                    }
                }
            }
        }
    }
}

// ---------------------------- fused CSR build -------------------------------
#define PA_CHUNK 4096
#define PA_SHIFT 9
#define PA_MAXB  256
#define HB_K     16

__global__ __launch_bounds__(256) void histB_kernel(
    const int* __restrict__ e0, const int* __restrict__ e1,
    const int* __restrict__ e2, int* __restrict__ bcnt, int E)
{
    __shared__ int lh[PA_MAXB];
    const int lab = blockIdx.y;
    const int* e = (lab == 0) ? e0 : (lab == 1) ? e1 : e2;
    const int t = threadIdx.x;
    for (int i = t; i < PA_MAXB; i += 256) lh[i] = 0;
    __syncthreads();
    const int base = blockIdx.x * 256 * HB_K;
#pragma unroll
    for (int k = 0; k < HB_K; ++k) {
        int i = base + k * 256 + t;
        if (i < E) atomicAdd(&lh[e[E + i] >> PA_SHIFT], 1);
    }
    __syncthreads();
    for (int i = t; i < PA_MAXB; i += 256)
        if (lh[i]) atomicAdd(&bcnt[i], lh[i]);
}

__global__ __launch_bounds__(256) void bscan_kernel(
    const int* __restrict__ bcnt, int* __restrict__ bbase)
{
    __shared__ int sd[PA_MAXB];
    const int t = threadIdx.x;
    sd[t] = bcnt[t];
    __syncthreads();
    int own = sd[t];
    for (int o = 1; o < 256; o <<= 1) {
        int v = (t >= o) ? sd[t - o] : 0;
        __syncthreads();
        sd[t] += v;
        __syncthreads();
    }
    bbase[t] = sd[t] - own;
}

__global__ __launch_bounds__(256) void placeA_kernel(
    const int* __restrict__ e0, const int* __restrict__ e1, const int* __restrict__ e2,
    const int* __restrict__ bbase, int* __restrict__ gres,
    int2* __restrict__ pairs, int E, int N)
{
    __shared__ int2 sStage[PA_CHUNK];
    __shared__ int sCnt[PA_MAXB], sScan[PA_MAXB], sCur[PA_MAXB], sGB[PA_MAXB];

    const int lab = blockIdx.y;
    const int t = threadIdx.x;
    const int base = blockIdx.x * PA_CHUNK;
    const int* e = (lab == 0) ? e0 : (lab == 1) ? e1 : e2;
    const int srcoff = lab * N;
    const int nbins = (N + (1 << PA_SHIFT) - 1) >> PA_SHIFT;

    for (int i = t; i < PA_MAXB; i += 256) { sCnt[i] = 0; sCur[i] = 0; }
    __syncthreads();

    int msrc[16], mdst[16];
    const int cnt_total = min(PA_CHUNK, E - base);
#pragma unroll
    for (int k = 0; k < 16; ++k) {
        int i = base + k * 256 + t;
        if (i < E) {
            msrc[k] = srcoff + e[i];
            int d = e[E + i];
            mdst[k] = d;
            atomicAdd(&sCnt[d >> PA_SHIFT], 1);
        } else mdst[k] = -1;
    }
    __syncthreads();

    sScan[t] = sCnt[t];
    __syncthreads();
    for (int o = 1; o < 256; o <<= 1) {
        int v = (t >= o) ? sScan[t - o] : 0;
        __syncthreads();
        sScan[t] += v;
        __syncthreads();
    }
    if (t < nbins && sCnt[t] > 0)
        sGB[t] = bbase[t] + atomicAdd(&gres[t], sCnt[t]);
    __syncthreads();

#pragma unroll
    for (int k = 0; k < 16; ++k) {
        if (mdst[k] >= 0) {
            int bin = mdst[k] >> PA_SHIFT;
            int r = atomicAdd(&sCur[bin], 1);
            sStage[(sScan[bin] - sCnt[bin]) + r] = make_int2(msrc[k], mdst[k]);
        }
    }
    __syncthreads();

    for (int i = t; i < cnt_total; i += 256) {
        int2 pr = sStage[i];
        int bin = pr.y >> PA_SHIFT;
        pairs[sGB[bin] + (i - (sScan[bin] - sCnt[bin]))] = pr;
    }
}

__global__ __launch_bounds__(512) void placeB_kernel(
    const int2* __restrict__ pairs, const int* __restrict__ bbase,
    const int* __restrict__ bcnt, int* __restrict__ offs,
    int* __restrict__ csr, int N, int nbins)
{
    __shared__ int sCnt[512], sScan[512], sFill[512];
    const int bin = blockIdx.x;
    const int t = threadIdx.x;
    const int n0 = bin << PA_SHIFT;
    const int n1 = min(n0 + 512, N);
    const int len = n1 - n0;
    const int rb  = bbase[bin];
    const int cnt = bcnt[bin];
    const int2* gp = pairs + rb;

    sCnt[t] = 0; sFill[t] = 0;
    __syncthreads();
    for (int i = t; i < cnt; i += 512)
        atomicAdd(&sCnt[gp[i].y - n0], 1);
    __syncthreads();
    sScan[t] = sCnt[t];
    __syncthreads();
    for (int o = 1; o < 512; o <<= 1) {
        int v = (t >= o) ? sScan[t - o] : 0;
        __syncthreads();
        sScan[t] += v;
        __syncthreads();
    }
    const int excl = sScan[t] - sCnt[t];
    if (t < len) offs[n0 + t] = rb + excl;
    if (bin == nbins - 1 && t == 0) offs[N] = rb + cnt;
    sScan[t] = excl;
    __syncthreads();

    for (int i = t; i < cnt; i += 512) {
        int2 pr = gp[i];
        int ln = pr.y - n0;
        int p = atomicAdd(&sFill[ln], 1);
        csr[rb + sScan[ln] + p] = pr.x;
    }
}

// ---------------------------- fused aggregation -----------------------------
__global__ __launch_bounds__(256) void agg3_kernel(
    const unsigned short* __restrict__ xtR,
    const unsigned char* __restrict__ xt3,
    const int* __restrict__ csr, const int* __restrict__ offs,
    unsigned short* __restrict__ hout, int N)
{
    int w = threadIdx.x >> 6, lane = threadIdx.x & 63;
    int dst = blockIdx.x * 4 + w;
    if (dst >= N) return;

    const ushort2* r2 = (const ushort2*)xtR;
    ushort2 rv = r2[(size_t)dst * 64 + lane];
    float2 a[8];
#pragma unroll
    for (int i = 0; i < 8; ++i) a[i] = make_float2(0.f, 0.f);

    const unsigned short* x8 = (const unsigned short*)xt3;
    const int beg = offs[dst], end = offs[dst + 1];
    int k = beg;
    for (; k + 8 <= end; k += 8) {
        int4 sa = *(const int4*)(csr + k);
        int4 sb = *(const int4*)(csr + k + 4);
        int s[8] = {sa.x, sa.y, sa.z, sa.w, sb.x, sb.y, sb.z, sb.w};
        unsigned short v[8];
#pragma unroll
        for (int i = 0; i < 8; ++i) v[i] = x8[(size_t)s[i] * 64 + lane];
#pragma unroll
        for (int i = 0; i < 8; ++i) {
            float2 f = up2fp8(v[i]);
            a[i].x += f.x; a[i].y += f.y;
        }
    }
    for (; k + 2 <= end; k += 2) {
        unsigned short v0 = x8[(size_t)csr[k] * 64 + lane];
        unsigned short v1 = x8[(size_t)csr[k + 1] * 64 + lane];
        float2 f0 = up2fp8(v0), f1 = up2fp8(v1);
        a[0].x += f0.x; a[0].y += f0.y;
        a[1].x += f1.x; a[1].y += f1.y;
    }
    for (; k < end; ++k) {
        float2 f0 = up2fp8(x8[(size_t)csr[k] * 64 + lane]);
        a[0].x += f0.x; a[0].y += f0.y;
    }
    float sx = ((a[0].x + a[1].x) + (a[2].x + a[3].x)) +
               ((a[4].x + a[5].x) + (a[6].x + a[7].x));
    float sy = ((a[0].y + a[1].y) + (a[2].y + a[3].y)) +
               ((a[4].y + a[5].y) + (a[6].y + a[7].y));
    float fx = bf2f(rv.x) + 0.0625f * sx;
    float fy = bf2f(rv.y) + 0.0625f * sy;
    ((unsigned*)hout)[(size_t)dst * 64 + lane] = pk2(fmaxf(fx, 0.f), fmaxf(fy, 0.f));
}

// ---------------------------- pool (+counts) / decoder ----------------------
__global__ __launch_bounds__(256) void pool_kernel(
    const unsigned short* __restrict__ in, const int* __restrict__ batch,
    float* __restrict__ gsum, float* __restrict__ gcnt, int N)
{
    int t = threadIdx.x;
    int j = t & 127, half = t >> 7;
    int n0 = blockIdx.x * 64 + half * 32;
    float acc = 0.f, c = 0.f; int cur = -1;
    for (int i = 0; i < 32; ++i) {
        int n = n0 + i;
        if (n >= N) break;
        int g = batch[n];
        if (g != cur) {
            if (cur >= 0) {
                atomicAdd(&gsum[cur * 128 + j], acc);
                if (j == 0) atomicAdd(&gcnt[cur], c);
            }
            cur = g; acc = 0.f; c = 0.f;
        }
        acc += bf2f(in[(size_t)n * 128 + j]);
        c += 1.f;
    }
    if (cur >= 0) {
        atomicAdd(&gsum[cur * 128 + j], acc);
        if (j == 0) atomicAdd(&gcnt[cur], c);
    }
}

__global__ __launch_bounds__(128) void dec_kernel(
    const float* __restrict__ gsum, const float* __restrict__ gcnt,
    const float* __restrict__ W1, const float* __restrict__ B1,
    const float* __restrict__ W2, const float* __restrict__ B2,
    float* __restrict__ out)
{
    __shared__ float sg[128];
    __shared__ float sh[128];
    int t = threadIdx.x, b = blockIdx.x;
    float cinv = 1.0f / fmaxf(gcnt[b], 1.0f);
    sg[t] = gsum[b * 128 + t] * cinv;
    __syncthreads();
    float acc = B1[t];
    for (int f = 0; f < 128; ++f) acc += sg[f] * W1[f * 128 + t];
    sh[t] = fmaxf(acc, 0.f) * W2[t];
    __syncthreads();
    for (int o = 64; o > 0; o >>= 1) {
        if (t < o) sh[t] += sh[t + o];
        __syncthreads();
    }
    if (t == 0) out[b] = sh[0] + B2[0];
}

// ---------------------------- launch ---------------------------------------
extern "C" void kernel_launch(void* const* d_in, const int* in_sizes, int n_in,
                              void* d_out, int out_size, void* d_ws, size_t ws_size,
                              hipStream_t stream)
{
    const float* x    = (const float*)d_in[0];
    const int*   e0   = (const int*)d_in[1];
    const int*   e1   = (const int*)d_in[2];
    const int*   e2   = (const int*)d_in[3];
    const int*   bat  = (const int*)d_in[4];
    const float* Wemb = (const float*)d_in[5];
    const float* qkv  = (const float*)d_in[6];
    const float* fw1  = (const float*)d_in[7];
    const float* fb1  = (const float*)d_in[8];
    const float* fw2  = (const float*)d_in[9];
    const float* fb2  = (const float*)d_in[10];
    const float* mw1  = (const float*)d_in[11];
    const float* mb1  = (const float*)d_in[12];
    const float* mw2  = (const float*)d_in[13];
    const float* mb2  = (const float*)d_in[14];
    const int N = in_sizes[0] / 112;
    const int E = in_sizes[1] / 2;
    float* outp = (float*)d_out;
    (void)n_in; (void)out_size; (void)ws_size;

    char* w = (char*)d_ws;
    auto alloc = [&](size_t bytes) {
        char* p = w; w += (bytes + 255) & ~(size_t)255; return p;
    };
    unsigned short* h0    = (unsigned short*)alloc((size_t)N * 128 * 2);
    unsigned short* h1    = (unsigned short*)alloc((size_t)N * 128 * 2);
    unsigned short* xtR   = (unsigned short*)alloc((size_t)N * 128 * 2);
    unsigned char*  xt3   = (unsigned char*)alloc((size_t)3 * N * 128);
    unsigned short* wpack = (unsigned short*)alloc(8 * 10 * 64 * 8 * 2);
    int*   csr   = (int*)alloc((size_t)3 * E * 4);
    int*   offs  = (int*)alloc((size_t)(N + 1) * 4);
    int*   bcnt  = (int*)alloc(PA_MAXB * 4);
    int*   bbase = (int*)alloc(PA_MAXB * 4);
    int*   gres  = (int*)alloc(PA_MAXB * 4);
    float* gsum  = (float*)alloc(64 * 128 * 4);
    float* gcnt  = (float*)alloc(64 * 4);
    int2* pairs = (int2*)xtR;   // aliased; consumed before attn4 writes xtR

    const int nbins = (N + (1 << PA_SHIFT) - 1) >> PA_SHIFT;

    wprep_kernel<<<8, 64, 0, stream>>>(qkv, fw1, fw2, wpack, bcnt, gres, gsum, gcnt);
    enc_kernel<<<(N + 7) / 8, 128, 0, stream>>>(x, Wemb, h0, N);

    histB_kernel<<<dim3((E + 256 * HB_K - 1) / (256 * HB_K), 3), 256, 0, stream>>>(
        e0, e1, e2, bcnt, E);
    bscan_kernel<<<1, 256, 0, stream>>>(bcnt, bbase);
    placeA_kernel<<<dim3((E + PA_CHUNK - 1) / PA_CHUNK, 3), 256, 0, stream>>>(
        e0, e1, e2, bbase, gres, pairs, E, N);
    placeB_kernel<<<nbins, 512, 0, stream>>>(pairs, bbase, bcnt, offs, csr, N, nbins);

    const int ATT_GRID = 768;   // 3 blocks/CU if LDS-residency permits
    auto run_layer = [&](const unsigned short* lin, unsigned short* lout, int l) {
        attn4_kernel<<<ATT_GRID, 256, 0, stream>>>(
            lin, xtR, xt3, wpack, fb1, fb2, l * 4, N);
        agg3_kernel<<<(N + 3) / 4, 256, 0, stream>>>(xtR, xt3, csr, offs, lout, N);
    };
    run_layer(h0, h1, 0);
    run_layer(h1, h0, 1);

    pool_kernel<<<(N + 63) / 64, 256, 0, stream>>>(h0, bat, gsum, gcnt, N);
    dec_kernel<<<64, 128, 0, stream>>>(gsum, gcnt, mw1, mb1, mw2, mb2, outp);
}